// Round 1
// baseline (5308.864 us; speedup 1.0000x reference)
//
#include <hip/hip_runtime.h>
#include <cstdint>

static constexpr int B2 = 2;
static constexpr int C = 512;
static constexpr int N = 4096;
static constexpr long CN = (long)C * N;
static constexpr float EPSC = 1e-5f;
static constexpr int KSEL = 308;       // N - int(N*0.925) survivors per batch
static constexpr int NS_ITERS = 12;

__device__ __forceinline__ float wredSum(float v){
#pragma unroll
  for (int o = 32; o >= 1; o >>= 1) v += __shfl_xor(v, o, 64);
  return v;
}
__device__ __forceinline__ float wredMax(float v){
#pragma unroll
  for (int o = 32; o >= 1; o >>= 1) v = fmaxf(v, __shfl_xor(v, o, 64));
  return v;
}

// ---- per-(b,c) normalize: DO_VAR=1 -> adain, DO_VAR=0 -> subtract mean only ----
template<int DO_VAR>
__global__ __launch_bounds__(256) void k_norm(const float* __restrict__ x, float* __restrict__ out){
  long bc = blockIdx.x;
  const float* px = x + bc * N;
  float* po = out + bc * N;
  int tid = threadIdx.x;
  float s1 = 0.f, s2 = 0.f;
  for (int i = tid; i < N; i += 256){ float v = px[i]; s1 += v; if (DO_VAR) s2 += v * v; }
  __shared__ float sh1[4], sh2[4];
  s1 = wredSum(s1);
  if (DO_VAR) s2 = wredSum(s2);
  if ((tid & 63) == 0){ sh1[tid >> 6] = s1; sh2[tid >> 6] = DO_VAR ? s2 : 0.f; }
  __syncthreads();
  float m = (sh1[0] + sh1[1] + sh1[2] + sh1[3]) * (1.f / (float)N);
  float r = 1.f;
  if (DO_VAR){
    float ex2 = (sh2[0] + sh2[1] + sh2[2] + sh2[3]) * (1.f / (float)N);
    float var = ex2 - m * m;
    r = rsqrtf((var > 0.f ? var : 0.f) + EPSC);
  }
  for (int i = tid; i < N; i += 256){
    float v = px[i] - m;
    po[i] = DO_VAR ? v * r : v;
  }
}

// ---- generic tiled fp32 GEMM: C[i,j] = alpha * sum_k opA(i,k)*opB(k,j) (+bias[i]) (+addsrc) ----
// TRA=0: A is [M,K] row-major ; TRA=1: A is [K,M] row-major
// TRB=0: B is [K,N] row-major ; TRB=1: B is [N,K] row-major
// TMH=1: epilogue v = (3*delta(i,j) - v) * 0.5  (Newton-Schulz helper)
template<int TRA, int TRB, int TMH>
__global__ __launch_bounds__(256) void k_gemm(
    const float* __restrict__ A, const float* __restrict__ B, float* __restrict__ Co,
    int M, int Nn, int K, long sA, long sB, long sC,
    float alpha, const float* __restrict__ alpha_ptr,
    const float* __restrict__ bias,
    const float* __restrict__ addsrc, long sAdd)
{
  __shared__ __align__(16) float As[16][68];
  __shared__ __align__(16) float Bs[16][68];
  const int z = blockIdx.z;
  const float* Ab = A + (long)z * sA;
  const float* Bb = B + (long)z * sB;
  float* Cb = Co + (long)z * sC;
  const int i0 = blockIdx.x * 64;
  const int j0 = blockIdx.y * 64;
  const int tid = threadIdx.x;
  float acc[4][4] = {{0.f}};
  for (int kt = 0; kt < K; kt += 16){
#pragma unroll
    for (int p = 0; p < 4; ++p){
      int idx = tid + p * 256;
      if (TRA == 0){
        int i = idx >> 4, kk = idx & 15;
        As[kk][i] = Ab[(long)(i0 + i) * K + (kt + kk)];
      } else {
        int kk = idx >> 6, i = idx & 63;
        As[kk][i] = Ab[(long)(kt + kk) * M + (i0 + i)];
      }
      if (TRB == 0){
        int kk = idx >> 6, j = idx & 63;
        Bs[kk][j] = Bb[(long)(kt + kk) * Nn + (j0 + j)];
      } else {
        int j = idx >> 4, kk = idx & 15;
        Bs[kk][j] = Bb[(long)(j0 + j) * K + (kt + kk)];
      }
    }
    __syncthreads();
    const int ty = tid >> 4, tx = tid & 15;
#pragma unroll
    for (int kk = 0; kk < 16; ++kk){
      const float4 av = *reinterpret_cast<const float4*>(&As[kk][ty * 4]);
      const float4 bv = *reinterpret_cast<const float4*>(&Bs[kk][tx * 4]);
      float aa[4] = {av.x, av.y, av.z, av.w};
      float bb[4] = {bv.x, bv.y, bv.z, bv.w};
#pragma unroll
      for (int r = 0; r < 4; ++r)
#pragma unroll
        for (int c2 = 0; c2 < 4; ++c2)
          acc[r][c2] = fmaf(aa[r], bb[c2], acc[r][c2]);
    }
    __syncthreads();
  }
  const int ty = tid >> 4, tx = tid & 15;
  float al = alpha;
  if (alpha_ptr) al *= alpha_ptr[z];
#pragma unroll
  for (int r = 0; r < 4; ++r){
    const int gi = i0 + ty * 4 + r;
    const float bval = bias ? bias[gi] : 0.f;
#pragma unroll
    for (int c2 = 0; c2 < 4; ++c2){
      const int gj = j0 + tx * 4 + c2;
      float v = acc[r][c2] * al;
      if (TMH) v = (((gi == gj) ? 3.f : 0.f) - v) * 0.5f;
      v += bval;
      if (addsrc) v += addsrc[(long)z * sAdd + (long)gi * Nn + gj];
      Cb[(long)gi * Nn + gj] = v;
    }
  }
}

template<int TRA, int TRB, int TMH>
static inline void launch_gemm(hipStream_t stream, const float* A, const float* B, float* Cp,
                               int M, int Nn, int K, long sA, long sB, long sC, int nz,
                               float alpha, const float* aptr, const float* bias,
                               const float* add, long sAdd){
  k_gemm<TRA, TRB, TMH><<<dim3(M / 64, Nn / 64, nz), dim3(256), 0, stream>>>(
      A, B, Cp, M, Nn, K, sA, sB, sC, alpha, aptr, bias, add, sAdd);
}

// ---- cov finish: add 2*EPS to diagonal, Gershgorin bound t[z] = max abs row sum ----
__global__ __launch_bounds__(128) void k_cov_finish(float* __restrict__ cov, unsigned int* __restrict__ tbits){
  const int r = blockIdx.x, z = blockIdx.y;
  float* row = cov + (long)z * C * C + (long)r * C;
  const int tid = threadIdx.x;
  float s = 0.f;
  for (int i = tid; i < C; i += 128){
    float v = row[i];
    if (i == r){ v += 2.f * EPSC; row[i] = v; }
    s += fabsf(v);
  }
  s = wredSum(s);
  __shared__ float sh[2];
  if ((tid & 63) == 0) sh[tid >> 6] = s;
  __syncthreads();
  if (tid == 0) atomicMax(tbits + z, __float_as_uint(sh[0] + sh[1]));
}

__global__ void k_scalars(const unsigned int* __restrict__ tbits, float* __restrict__ invt, float* __restrict__ invsqt){
  int z = threadIdx.x;
  if (z < 4){
    float t = __uint_as_float(tbits[z]);
    invt[z] = 1.f / t;
    invsqt[z] = rsqrtf(t);
  }
}

__global__ __launch_bounds__(256) void k_ns_init(const float* __restrict__ cov, const float* __restrict__ invt,
                                                 float* __restrict__ Y, float* __restrict__ Z){
  const int r = blockIdx.x, z = blockIdx.y;
  const long base = (long)z * C * C + (long)r * C;
  const float it = invt[z];
  for (int i = threadIdx.x; i < C; i += 256){
    Y[base + i] = cov[base + i] * it;
    Z[base + i] = (i == r) ? 1.f : 0.f;
  }
}

// ---- per-row softmax stats. MASKED: also masked sum -> scale = 1/(S*max(Sm/S,1e-12)) ----
template<int MASKED>
__global__ __launch_bounds__(256) void k_rowstats(
    const float* __restrict__ E, const float* __restrict__ mx, const float* __restrict__ my,
    float* __restrict__ rowmax, float* __restrict__ rowscale)
{
  const int row = blockIdx.x;
  const float* pe = E + (long)row * N;
  const int tid = threadIdx.x;
  __shared__ float sh[4], shb[4];
  float mv = -3.4e38f;
  for (int i = tid; i < N; i += 256) mv = fmaxf(mv, pe[i]);
  mv = wredMax(mv);
  if ((tid & 63) == 0) sh[tid >> 6] = mv;
  __syncthreads();
  const float M_ = fmaxf(fmaxf(sh[0], sh[1]), fmaxf(sh[2], sh[3]));
  const float target = MASKED ? mx[row] : 0.f;
  float s = 0.f, sm = 0.f;
  for (int i = tid; i < N; i += 256){
    float ev = expf(pe[i] - M_);
    s += ev;
    if (MASKED && my[i] == target) sm += ev;
  }
  __syncthreads();
  s = wredSum(s);
  if (MASKED) sm = wredSum(sm);
  if ((tid & 63) == 0){ sh[tid >> 6] = s; shb[tid >> 6] = sm; }
  __syncthreads();
  if (tid == 0){
    float S = sh[0] + sh[1] + sh[2] + sh[3];
    if (MASKED){
      float Sm = shb[0] + shb[1] + shb[2] + shb[3];
      float l1 = Sm / S;
      if (l1 < 1e-12f) l1 = 1e-12f;
      rowscale[row] = 1.f / (S * l1);
    } else {
      rowscale[row] = 1.f / S;
    }
    rowmax[row] = M_;
  }
}

// ---- overwrite energy with final masked+normalized correlation weights ----
__global__ __launch_bounds__(256) void k_wmask(
    float* __restrict__ E, const float* __restrict__ mx, const float* __restrict__ my,
    const float* __restrict__ rowmax, const float* __restrict__ rowscale)
{
  const int row = blockIdx.x;
  const int j = blockIdx.y * 256 + threadIdx.x;
  const float target = mx[row];
  const float rm = rowmax[row], rs = rowscale[row];
  const long idx = (long)row * N + j;
  const float e = E[idx];
  E[idx] = (my[j] == target) ? expf(e - rm) * rs : 0.f;
}

// ---- column accumulation of softmax (atten) ----
__global__ __launch_bounds__(256) void k_colaccum(const float* __restrict__ E, const float* __restrict__ rowmax,
                                                  const float* __restrict__ rowscale, float* __restrict__ partials){
  const int j = blockIdx.x * 256 + threadIdx.x;
  const int r0 = blockIdx.y * 128;
  float acc = 0.f;
  for (int r2 = r0; r2 < r0 + 128; ++r2){
    acc += expf(E[(long)r2 * N + j] - rowmax[r2]) * rowscale[r2];
  }
  partials[(long)blockIdx.y * N + j] = acc;
}

__global__ __launch_bounds__(256) void k_colreduce(const float* __restrict__ partials, float* __restrict__ att){
  const int j = blockIdx.x * 256 + threadIdx.x;
  float s = 0.f;
  for (int c2 = 0; c2 < 32; ++c2) s += partials[(long)c2 * N + j];
  att[j] = s * (1.f / (float)N);
}

// ---- exact KSEL-th largest via radix select on positive-float bits; one block per batch ----
__global__ __launch_bounds__(256) void k_radix(const float* __restrict__ a, float* __restrict__ thr){
  __shared__ unsigned int vals[N];
  __shared__ float shc[4];
  __shared__ unsigned int p_sh;
  __shared__ int k_sh;
  const float* pa = a + (long)blockIdx.x * N;
  const int tid = threadIdx.x;
  for (int i = tid; i < N; i += 256) vals[i] = __float_as_uint(pa[i]);
  if (tid == 0){ p_sh = 0u; k_sh = KSEL; }
  __syncthreads();
  for (int b = 31; b >= 0; --b){
    const unsigned int bit = 1u << b;
    const unsigned int above = (b == 31) ? 0u : ~((bit << 1) - 1u);
    const unsigned int p = p_sh;
    int cnt = 0;
    for (int i = tid; i < N; i += 256){
      unsigned int v = vals[i];
      if ((v & above) == p && (v & bit)) cnt++;
    }
    float cf = wredSum((float)cnt);
    if ((tid & 63) == 0) shc[tid >> 6] = cf;
    __syncthreads();
    if (tid == 0){
      int c1 = (int)(shc[0] + shc[1] + shc[2] + shc[3] + 0.5f);
      if (k_sh <= c1) p_sh = p | bit;
      else k_sh -= c1;
    }
    __syncthreads();
  }
  if (tid == 0) thr[blockIdx.x] = __uint_as_float(p_sh);
}

__global__ __launch_bounds__(256) void k_mask(const float* __restrict__ ax, const float* __restrict__ ay,
                                              const float* __restrict__ thr, float* __restrict__ mx,
                                              float* __restrict__ my){
  int j = blockIdx.x * 256 + threadIdx.x;
  mx[j] = (ax[j] >= thr[0] && ax[N + j] >= thr[1]) ? 1.f : 0.f;
  my[j] = (ay[j] >= thr[2] && ay[N + j] >= thr[3]) ? 1.f : 0.f;
}

extern "C" void kernel_launch(void* const* d_in, const int* in_sizes, int n_in,
                              void* d_out, int out_size, void* d_ws, size_t ws_size,
                              hipStream_t stream)
{
  const float* x     = (const float*)d_in[0];
  const float* y     = (const float*)d_in[1];
  const float* f_w   = (const float*)d_in[2];
  const float* f_b   = (const float*)d_in[3];
  const float* g_w   = (const float*)d_in[4];
  const float* g_b   = (const float*)d_in[5];
  const float* saf_w = (const float*)d_in[6];
  const float* saf_b = (const float*)d_in[7];
  const float* sag_w = (const float*)d_in[8];
  const float* sag_b = (const float*)d_in[9];
  const float* h_w   = (const float*)d_in[10];
  const float* h_b   = (const float*)d_in[11];
  const float* ow    = (const float*)d_in[12];
  const float* ob    = (const float*)d_in[13];

  float* W = (float*)d_ws;
  float* xa = W;                       // [B,C,N] adain(x)
  float* ya = xa + B2 * CN;            // adain(y)
  float* xz = ya + B2 * CN;            // zca(x), later residual
  float* yz = xz + B2 * CN;            // zca(y)
  float* tA = yz + B2 * CN;            // fc_x / f
  float* tB = tA + B2 * CN;            // fc_y / g
  float* tH = tB + B2 * CN;            // h
  float* energy = tH + B2 * CN;        // [N,N]
  float* covb = energy + (long)N * N;  // 4 x [C,C]  (x b0, x b1, y b0, y b1)
  float* Y0 = covb + 4L * C * C;
  float* Z0 = Y0 + 4L * C * C;
  float* Y1 = Z0 + 4L * C * C;
  float* Z1 = Y1 + 4L * C * C;
  float* Tm = Z1 + 4L * C * C;
  float* rm  = Tm + 4L * C * C;        // [N]
  float* rsc = rm + N;                 // [N]
  float* partials = rsc + N;           // [32,N]
  float* mxv = partials + 32L * N;     // [N]
  float* myv = mxv + N;                // [N]
  float* thr = myv + N;                // [4]
  float* invt = thr + 4;               // [4]
  float* invsqt = invt + 4;            // [4]
  unsigned int* tbits = (unsigned int*)(invsqt + 4); // [4]
  size_t need_bytes = (size_t)(((invsqt + 8) - W)) * sizeof(float);
  if (ws_size < need_bytes) return;

  float* outm = (float*)d_out;            // [B,C,N]
  float* attx = outm + B2 * CN;           // [B,N]
  float* atty = attx + (long)B2 * N;      // [B,N]

  const long CC2 = (long)C * C;

  // 1) adain norms + zca centering
  k_norm<1><<<dim3(B2 * C), dim3(256), 0, stream>>>(x, xa);
  k_norm<1><<<dim3(B2 * C), dim3(256), 0, stream>>>(y, ya);
  k_norm<0><<<dim3(B2 * C), dim3(256), 0, stream>>>(x, tA);
  k_norm<0><<<dim3(B2 * C), dim3(256), 0, stream>>>(y, tB);

  // 2) covariances (+2*EPS*I via finish), Gershgorin normalization
  launch_gemm<0,1,0>(stream, tA, tA, covb,            C, C, N, CN, CN, CC2, 2, 1.f / (float)(N - 1), nullptr, nullptr, nullptr, 0);
  launch_gemm<0,1,0>(stream, tB, tB, covb + 2 * CC2,  C, C, N, CN, CN, CC2, 2, 1.f / (float)(N - 1), nullptr, nullptr, nullptr, 0);
  hipMemsetAsync(tbits, 0, 4 * sizeof(unsigned int), stream);
  k_cov_finish<<<dim3(C, 4), dim3(128), 0, stream>>>(covb, tbits);
  k_scalars<<<dim3(1), dim3(8), 0, stream>>>(tbits, invt, invsqt);
  k_ns_init<<<dim3(C, 4), dim3(256), 0, stream>>>(covb, invt, Y0, Z0);

  // 3) Newton-Schulz: Z -> (cov/t)^(-1/2)
  float *Yc = Y0, *Zc = Z0, *Yn = Y1, *Zn = Z1;
  for (int it = 0; it < NS_ITERS; ++it){
    launch_gemm<0,0,1>(stream, Zc, Yc, Tm, C, C, C, CC2, CC2, CC2, 4, 1.f, nullptr, nullptr, nullptr, 0);
    launch_gemm<0,0,0>(stream, Yc, Tm, Yn, C, C, C, CC2, CC2, CC2, 4, 1.f, nullptr, nullptr, nullptr, 0);
    launch_gemm<0,0,0>(stream, Tm, Zc, Zn, C, C, C, CC2, CC2, CC2, 4, 1.f, nullptr, nullptr, nullptr, 0);
    float* t1 = Yc; Yc = Yn; Yn = t1;
    float* t2 = Zc; Zc = Zn; Zn = t2;
  }

  // 4) zca outputs: xz = (1/sqrt(t)) * Z * fc
  launch_gemm<0,0,0>(stream, Zc,           tA, xz, C, N, C, CC2, CN, CN, 2, 1.f, invsqt,     nullptr, nullptr, 0);
  launch_gemm<0,0,0>(stream, Zc + 2 * CC2, tB, yz, C, N, C, CC2, CN, CN, 2, 1.f, invsqt + 2, nullptr, nullptr, 0);

  // 5) self-attention blocks -> atten
  auto self_block = [&](const float* zin, float* att_out){
    launch_gemm<0,0,0>(stream, saf_w, zin, tA, C, N, C, 0, CN, CN, 2, 1.f, nullptr, saf_b, nullptr, 0);
    launch_gemm<0,0,0>(stream, sag_w, zin, tB, C, N, C, 0, CN, CN, 2, 1.f, nullptr, sag_b, nullptr, 0);
    for (int b = 0; b < B2; ++b){
      launch_gemm<1,0,0>(stream, tA + (long)b * CN, tB + (long)b * CN, energy, N, N, C, 0, 0, 0, 1, 1.f, nullptr, nullptr, nullptr, 0);
      k_rowstats<0><<<dim3(N), dim3(256), 0, stream>>>(energy, nullptr, nullptr, rm, rsc);
      k_colaccum<<<dim3(16, 32), dim3(256), 0, stream>>>(energy, rm, rsc, partials);
      k_colreduce<<<dim3(16), dim3(256), 0, stream>>>(partials, att_out + (long)b * N);
    }
  };
  self_block(xz, attx);
  self_block(yz, atty);

  // 6) masks
  k_radix<<<dim3(2), dim3(256), 0, stream>>>(attx, thr);
  k_radix<<<dim3(2), dim3(256), 0, stream>>>(atty, thr + 2);
  k_mask<<<dim3(16), dim3(256), 0, stream>>>(attx, atty, thr, mxv, myv);

  // 7) main correlation + residual + output
  launch_gemm<0,0,0>(stream, f_w, xa, tA, C, N, C, 0, CN, CN, 2, 1.f, nullptr, f_b, nullptr, 0);
  launch_gemm<0,0,0>(stream, g_w, ya, tB, C, N, C, 0, CN, CN, 2, 1.f, nullptr, g_b, nullptr, 0);
  launch_gemm<0,0,0>(stream, h_w, y,  tH, C, N, C, 0, CN, CN, 2, 1.f, nullptr, h_b, nullptr, 0);
  for (int b = 0; b < B2; ++b){
    launch_gemm<1,0,0>(stream, tA + (long)b * CN, tB + (long)b * CN, energy, N, N, C, 0, 0, 0, 1, 1.f, nullptr, nullptr, nullptr, 0);
    k_rowstats<1><<<dim3(N), dim3(256), 0, stream>>>(energy, mxv, myv, rm, rsc);
    k_wmask<<<dim3(N, 16), dim3(256), 0, stream>>>(energy, mxv, myv, rm, rsc);
    launch_gemm<0,1,0>(stream, tH + (long)b * CN, energy, xz + (long)b * CN, C, N, N, 0, 0, 0, 1, 1.f, nullptr, nullptr, nullptr, 0);
    launch_gemm<0,0,0>(stream, ow, xz + (long)b * CN, outm + (long)b * CN, C, N, C, 0, 0, 0, 1, 1.f, nullptr, ob, x + (long)b * CN, 0);
  }
}

// Round 2
// 2996.421 us; speedup vs baseline: 1.7717x; 1.7717x over previous
//
#include <hip/hip_runtime.h>
#include <cstdint>

static constexpr int B2 = 2;
static constexpr int C = 512;
static constexpr int N = 4096;
static constexpr long CN = (long)C * N;     // per-batch channel-major plane
static constexpr long NC = (long)N * C;     // per-batch pixel-major plane
static constexpr long CC = (long)C * C;
static constexpr float EPSC = 1e-5f;
static constexpr int KSEL = 308;            // N - int(N*0.925)
static constexpr int NS_ITERS = 12;

typedef __attribute__((ext_vector_type(8))) __bf16 bf16x8;
typedef __attribute__((ext_vector_type(4))) float f32x4;

__device__ __forceinline__ float wredSum(float v){
#pragma unroll
  for (int o = 32; o >= 1; o >>= 1) v += __shfl_xor(v, o, 64);
  return v;
}
__device__ __forceinline__ float wredMax(float v){
#pragma unroll
  for (int o = 32; o >= 1; o >>= 1) v = fmaxf(v, __shfl_xor(v, o, 64));
  return v;
}

__device__ __forceinline__ void gld16(const __bf16* g, __bf16* l){
  __builtin_amdgcn_global_load_lds(
      (const __attribute__((address_space(1))) void*)g,
      (__attribute__((address_space(3))) void*)l, 16, 0, 0);
}

__device__ __forceinline__ void splitw(float v, __bf16* ph, __bf16* pl, long o){
  __bf16 h = (__bf16)v;
  ph[o] = h;
  pl[o] = (__bf16)(v - (float)h);
}

// ======================= split-bf16 MFMA GEMM =======================
// C[i,j] = alpha * sum_k (Ah+Al)[i,k] * (Bh+Bl)[j,k]   (A:[M,K], B:[N,K] row-major)
// 3-pass: hh + hl + lh (lo*lo dropped, ~2^-16 rel). BM=BN=128, BK=32.
template<int TMH, int OUTMODE>
__global__ __launch_bounds__(256) void k_mm(
    const __bf16* __restrict__ Ah, const __bf16* __restrict__ Al,
    const __bf16* __restrict__ Bh, const __bf16* __restrict__ Bl,
    float* __restrict__ Cf, __bf16* __restrict__ Coh, __bf16* __restrict__ Col,
    int M, int Nn, int K,
    long sAz, long sBz, long sCz,
    float alpha, const float* __restrict__ alpha_ptr,
    const float* __restrict__ bias_row, const float* __restrict__ bias_col,
    const float* __restrict__ addsrc, long sAddz)
{
  __shared__ __align__(16) __bf16 sm[4][128 * 32];
  const int z = blockIdx.z;
  const int i0 = blockIdx.x * 128;
  const int j0 = blockIdx.y * 128;
  const int tid = threadIdx.x;
  const int lane = tid & 63;
  const int w = tid >> 6;
  const int wr = (w >> 1) * 64, wc = (w & 1) * 64;
  const int lr = lane & 15;
  const int g = lane >> 4;

  const __bf16* pAh = Ah + (long)z * sAz + (long)i0 * K;
  const __bf16* pAl = Al + (long)z * sAz + (long)i0 * K;
  const __bf16* pBh = Bh + (long)z * sBz + (long)j0 * K;
  const __bf16* pBl = Bl + (long)z * sBz + (long)j0 * K;

  f32x4 acc[4][4] = {};

  for (int kt = 0; kt < K; kt += 32){
#pragma unroll
    for (int p = 0; p < 2; ++p){
      const int t2 = p * 256 + tid;
      const int row = t2 >> 2;
      const int gs = (t2 & 3) ^ ((row >> 1) & 3);       // XOR-swizzled source granule
      const long go = (long)row * K + kt + gs * 8;
      gld16(pAh + go, &sm[0][t2 * 8]);
      gld16(pAl + go, &sm[1][t2 * 8]);
      gld16(pBh + go, &sm[2][t2 * 8]);
      gld16(pBl + go, &sm[3][t2 * 8]);
    }
    __syncthreads();
    bf16x8 fa[4], fal[4], fb[4], fbl[4];
#pragma unroll
    for (int mi = 0; mi < 4; ++mi){
      const int row = wr + mi * 16 + lr;
      const int off = row * 32 + ((g ^ ((row >> 1) & 3)) * 8);
      fa[mi]  = *(const bf16x8*)(&sm[0][off]);
      fal[mi] = *(const bf16x8*)(&sm[1][off]);
    }
#pragma unroll
    for (int ni = 0; ni < 4; ++ni){
      const int row = wc + ni * 16 + lr;
      const int off = row * 32 + ((g ^ ((row >> 1) & 3)) * 8);
      fb[ni]  = *(const bf16x8*)(&sm[2][off]);
      fbl[ni] = *(const bf16x8*)(&sm[3][off]);
    }
#pragma unroll
    for (int mi = 0; mi < 4; ++mi)
#pragma unroll
      for (int ni = 0; ni < 4; ++ni){
        acc[mi][ni] = __builtin_amdgcn_mfma_f32_16x16x32_bf16(fa[mi],  fb[ni],  acc[mi][ni], 0, 0, 0);
        acc[mi][ni] = __builtin_amdgcn_mfma_f32_16x16x32_bf16(fa[mi],  fbl[ni], acc[mi][ni], 0, 0, 0);
        acc[mi][ni] = __builtin_amdgcn_mfma_f32_16x16x32_bf16(fal[mi], fb[ni],  acc[mi][ni], 0, 0, 0);
      }
    __syncthreads();
  }

  float al2 = alpha;
  if (alpha_ptr) al2 *= alpha_ptr[z];
#pragma unroll
  for (int mi = 0; mi < 4; ++mi){
#pragma unroll
    for (int ni = 0; ni < 4; ++ni){
      const int col = j0 + wc + ni * 16 + lr;
      const float bc = bias_col ? bias_col[col] : 0.f;
#pragma unroll
      for (int j = 0; j < 4; ++j){
        const int row = i0 + wr + mi * 16 + g * 4 + j;
        float v = acc[mi][ni][j] * al2;
        if (TMH) v = (((row == col) ? 3.f : 0.f) - v) * 0.5f;
        if (bias_row) v += bias_row[row];
        v += bc;
        if (addsrc) v += addsrc[(long)z * sAddz + (long)row * Nn + col];
        const long o = (long)z * sCz + (long)row * Nn + col;
        if (OUTMODE == 0){ Cf[o] = v; }
        else { __bf16 h = (__bf16)v; Coh[o] = h; Col[o] = (__bf16)(v - (float)h); }
      }
    }
  }
}

template<int TMH, int OUTMODE>
static inline void mm(hipStream_t st,
                      const __bf16* Ah, const __bf16* Al, const __bf16* Bh, const __bf16* Bl,
                      float* Cf, __bf16* Coh, __bf16* Col,
                      int M, int Nn, int K, long sAz, long sBz, long sCz, int nz,
                      float alpha, const float* aptr, const float* brow, const float* bcol,
                      const float* add, long sAdd){
  k_mm<TMH, OUTMODE><<<dim3(M / 128, Nn / 128, nz), dim3(256), 0, st>>>(
      Ah, Al, Bh, Bl, Cf, Coh, Col, M, Nn, K, sAz, sBz, sCz,
      alpha, aptr, brow, bcol, add, sAdd);
}

// ======================= fp32 fallback GEMM (verified round-1) =======================
template<int TRA, int TRB, int TMH>
__global__ __launch_bounds__(256) void k_gemm(
    const float* __restrict__ A, const float* __restrict__ B, float* __restrict__ Co,
    int M, int Nn, int K, long sA, long sB, long sC,
    float alpha, const float* __restrict__ alpha_ptr,
    const float* __restrict__ bias,
    const float* __restrict__ addsrc, long sAdd)
{
  __shared__ __align__(16) float As[16][68];
  __shared__ __align__(16) float Bs[16][68];
  const int z = blockIdx.z;
  const float* Ab = A + (long)z * sA;
  const float* Bb = B + (long)z * sB;
  float* Cb = Co + (long)z * sC;
  const int i0 = blockIdx.x * 64;
  const int j0 = blockIdx.y * 64;
  const int tid = threadIdx.x;
  float acc[4][4] = {{0.f}};
  for (int kt = 0; kt < K; kt += 16){
#pragma unroll
    for (int p = 0; p < 4; ++p){
      int idx = tid + p * 256;
      if (TRA == 0){
        int i = idx >> 4, kk = idx & 15;
        As[kk][i] = Ab[(long)(i0 + i) * K + (kt + kk)];
      } else {
        int kk = idx >> 6, i = idx & 63;
        As[kk][i] = Ab[(long)(kt + kk) * M + (i0 + i)];
      }
      if (TRB == 0){
        int kk = idx >> 6, j = idx & 63;
        Bs[kk][j] = Bb[(long)(kt + kk) * Nn + (j0 + j)];
      } else {
        int j = idx >> 4, kk = idx & 15;
        Bs[kk][j] = Bb[(long)(j0 + j) * K + (kt + kk)];
      }
    }
    __syncthreads();
    const int ty = tid >> 4, tx = tid & 15;
#pragma unroll
    for (int kk = 0; kk < 16; ++kk){
      const float4 av = *reinterpret_cast<const float4*>(&As[kk][ty * 4]);
      const float4 bv = *reinterpret_cast<const float4*>(&Bs[kk][tx * 4]);
      float aa[4] = {av.x, av.y, av.z, av.w};
      float bb[4] = {bv.x, bv.y, bv.z, bv.w};
#pragma unroll
      for (int r = 0; r < 4; ++r)
#pragma unroll
        for (int c2 = 0; c2 < 4; ++c2)
          acc[r][c2] = fmaf(aa[r], bb[c2], acc[r][c2]);
    }
    __syncthreads();
  }
  const int ty = tid >> 4, tx = tid & 15;
  float al = alpha;
  if (alpha_ptr) al *= alpha_ptr[z];
#pragma unroll
  for (int r = 0; r < 4; ++r){
    const int gi = i0 + ty * 4 + r;
    const float bval = bias ? bias[gi] : 0.f;
#pragma unroll
    for (int c2 = 0; c2 < 4; ++c2){
      const int gj = j0 + tx * 4 + c2;
      float v = acc[r][c2] * al;
      if (TMH) v = (((gi == gj) ? 3.f : 0.f) - v) * 0.5f;
      v += bval;
      if (addsrc) v += addsrc[(long)z * sAdd + (long)gi * Nn + gj];
      Cb[(long)gi * Nn + gj] = v;
    }
  }
}

// ======================= prep / stats =======================
__global__ __launch_bounds__(256) void k_stats(const float* __restrict__ x, const float* __restrict__ y,
                                               float* __restrict__ meanv, float* __restrict__ invs){
  const int bid = blockIdx.x;           // 0..4*C-1
  const int t = bid >> 9, c = bid & 511;
  const float* src = (t < 2 ? x : y) + (long)(t & 1) * CN + (long)c * N;
  const int tid = threadIdx.x;
  float s1 = 0.f, s2 = 0.f;
  for (int i = tid; i < N; i += 256){ float v = src[i]; s1 += v; s2 += v * v; }
  __shared__ float sh1[4], sh2[4];
  s1 = wredSum(s1); s2 = wredSum(s2);
  if ((tid & 63) == 0){ sh1[tid >> 6] = s1; sh2[tid >> 6] = s2; }
  __syncthreads();
  if (tid == 0){
    float m = (sh1[0] + sh1[1] + sh1[2] + sh1[3]) * (1.f / (float)N);
    float ex2 = (sh2[0] + sh2[1] + sh2[2] + sh2[3]) * (1.f / (float)N);
    float var = ex2 - m * m;
    meanv[t * C + c] = m;
    invs[t * C + c] = rsqrtf((var > 0.f ? var : 0.f) + EPSC);
  }
}

// transpose [C,4096] fp32 -> pixel-major [4096,C] bf16-pairs: adain, centered, (raw)
__global__ __launch_bounds__(256) void k_prep(const float* __restrict__ src,
                                              const float* __restrict__ meanv, const float* __restrict__ invs, int toff,
                                              __bf16* __restrict__ adH, __bf16* __restrict__ adL,
                                              __bf16* __restrict__ ceH, __bf16* __restrict__ ceL,
                                              __bf16* __restrict__ rwH, __bf16* __restrict__ rwL){
  __shared__ float tile[64][65];
  const int z = blockIdx.z;
  const int n0 = blockIdx.x * 64;
  const int c0 = blockIdx.y * 64;
  const int tid = threadIdx.x;
  const int tx = tid & 63, ty = tid >> 6;
#pragma unroll
  for (int it = 0; it < 16; ++it){
    const int cc = it * 4 + ty;
    tile[cc][tx] = src[(long)z * CN + (long)(c0 + cc) * N + n0 + tx];
  }
  __syncthreads();
  const int tgt = toff + z;
  const float m = meanv[tgt * C + c0 + tx];
  const float r = invs[tgt * C + c0 + tx];
#pragma unroll
  for (int it = 0; it < 16; ++it){
    const int p = it * 4 + ty;
    const float v = tile[tx][p];
    const float cen = v - m;
    const long o = (long)z * NC + (long)(n0 + p) * C + c0 + tx;
    splitw(cen * r, adH, adL, o);
    splitw(cen, ceH, ceL, o);
    if (rwH) splitw(v, rwH, rwL, o);
  }
}

__global__ __launch_bounds__(256) void k_wcvt(const float* __restrict__ s, __bf16* __restrict__ h,
                                              __bf16* __restrict__ l, int n){
  int i = blockIdx.x * 256 + threadIdx.x;
  if (i < n) splitw(s[i], h, l, i);
}

__global__ __launch_bounds__(256) void k_pair2f(const __bf16* __restrict__ h, const __bf16* __restrict__ l,
                                                float* __restrict__ o, int n){
  int i = blockIdx.x * 256 + threadIdx.x;
  if (i < n) o[i] = (float)h[i] + (float)l[i];
}

// ======================= cov finish / NS init =======================
__global__ __launch_bounds__(128) void k_cov_finish(float* __restrict__ cov, const float* __restrict__ meanv,
                                                    unsigned int* __restrict__ tbits){
  const int r = blockIdx.x, z = blockIdx.y;
  float* row = cov + (long)z * CC + (long)r * C;
  const float mr = meanv[z * C + r];
  const float cmul = (float)N / (float)(N - 1);
  const int tid = threadIdx.x;
  float s = 0.f;
  for (int i = tid; i < C; i += 128){
    float v = row[i] - cmul * mr * meanv[z * C + i];
    if (i == r) v += 2.f * EPSC;
    row[i] = v;
    s += fabsf(v);
  }
  s = wredSum(s);
  __shared__ float sh[2];
  if ((tid & 63) == 0) sh[tid >> 6] = s;
  __syncthreads();
  if (tid == 0) atomicMax(tbits + z, __float_as_uint(sh[0] + sh[1]));
}

__global__ void k_scalars(const unsigned int* __restrict__ tbits, float* __restrict__ invt, float* __restrict__ invsqt){
  int z = threadIdx.x;
  if (z < 4){
    float t = __uint_as_float(tbits[z]);
    invt[z] = 1.f / t;
    invsqt[z] = rsqrtf(t);
  }
}

__global__ __launch_bounds__(256) void k_ns_init(const float* __restrict__ cov, const float* __restrict__ invt,
                                                 __bf16* __restrict__ Yh, __bf16* __restrict__ Yl,
                                                 __bf16* __restrict__ Zh, __bf16* __restrict__ Zl){
  const int r = blockIdx.x, z = blockIdx.y;
  const long base = (long)z * CC + (long)r * C;
  const float it = invt[z];
  for (int i = threadIdx.x; i < C; i += 256){
    splitw(cov[base + i] * it, Yh, Yl, base + i);
    Zh[base + i] = (__bf16)((i == r) ? 1.f : 0.f);
    Zl[base + i] = (__bf16)0.f;
  }
}

// ======================= softmax aux =======================
template<int MASKED>
__global__ __launch_bounds__(256) void k_rowstats(
    const float* __restrict__ E, const float* __restrict__ mx, const float* __restrict__ my,
    float* __restrict__ rowmax, float* __restrict__ rowscale)
{
  const int row = blockIdx.x;
  const float* pe = E + (long)row * N;
  const int tid = threadIdx.x;
  __shared__ float sh[4], shb[4];
  float mv = -3.4e38f;
  for (int i = tid; i < N; i += 256) mv = fmaxf(mv, pe[i]);
  mv = wredMax(mv);
  if ((tid & 63) == 0) sh[tid >> 6] = mv;
  __syncthreads();
  const float M_ = fmaxf(fmaxf(sh[0], sh[1]), fmaxf(sh[2], sh[3]));
  const float target = MASKED ? mx[row] : 0.f;
  float s = 0.f, smv = 0.f;
  for (int i = tid; i < N; i += 256){
    float ev = expf(pe[i] - M_);
    s += ev;
    if (MASKED && my[i] == target) smv += ev;
  }
  __syncthreads();
  s = wredSum(s);
  if (MASKED) smv = wredSum(smv);
  if ((tid & 63) == 0){ sh[tid >> 6] = s; shb[tid >> 6] = smv; }
  __syncthreads();
  if (tid == 0){
    float S = sh[0] + sh[1] + sh[2] + sh[3];
    if (MASKED){
      float Sm = shb[0] + shb[1] + shb[2] + shb[3];
      float l1 = Sm / S;
      if (l1 < 1e-12f) l1 = 1e-12f;
      rowscale[row] = 1.f / (S * l1);
    } else {
      rowscale[row] = 1.f / S;
    }
    rowmax[row] = M_;
  }
}

__global__ __launch_bounds__(256) void k_wmask(
    const float* __restrict__ E, const float* __restrict__ mx, const float* __restrict__ my,
    const float* __restrict__ rowmax, const float* __restrict__ rowscale,
    __bf16* __restrict__ ch, __bf16* __restrict__ cl)
{
  const int row = blockIdx.x;
  const int j = blockIdx.y * 256 + threadIdx.x;
  const float target = mx[row];
  const float rm = rowmax[row], rs = rowscale[row];
  const long idx = (long)row * N + j;
  const float v = (my[j] == target) ? expf(E[idx] - rm) * rs : 0.f;
  splitw(v, ch, cl, idx);
}

__global__ __launch_bounds__(256) void k_colaccum(const float* __restrict__ E, const float* __restrict__ rowmax,
                                                  const float* __restrict__ rowscale, float* __restrict__ partials){
  const int j = blockIdx.x * 256 + threadIdx.x;
  const int r0 = blockIdx.y * 128;
  float acc = 0.f;
  for (int r2 = r0; r2 < r0 + 128; ++r2){
    acc += expf(E[(long)r2 * N + j] - rowmax[r2]) * rowscale[r2];
  }
  partials[(long)blockIdx.y * N + j] = acc;
}

__global__ __launch_bounds__(256) void k_colreduce(const float* __restrict__ partials, float* __restrict__ att){
  const int j = blockIdx.x * 256 + threadIdx.x;
  float s = 0.f;
  for (int c2 = 0; c2 < 32; ++c2) s += partials[(long)c2 * N + j];
  att[j] = s * (1.f / (float)N);
}

// ======================= mask (radix select) =======================
__global__ __launch_bounds__(256) void k_radix(const float* __restrict__ a, float* __restrict__ thr){
  __shared__ unsigned int vals[N];
  __shared__ float shc[4];
  __shared__ unsigned int p_sh;
  __shared__ int k_sh;
  const float* pa = a + (long)blockIdx.x * N;
  const int tid = threadIdx.x;
  for (int i = tid; i < N; i += 256) vals[i] = __float_as_uint(pa[i]);
  if (tid == 0){ p_sh = 0u; k_sh = KSEL; }
  __syncthreads();
  for (int b = 31; b >= 0; --b){
    const unsigned int bit = 1u << b;
    const unsigned int above = (b == 31) ? 0u : ~((bit << 1) - 1u);
    const unsigned int p = p_sh;
    int cnt = 0;
    for (int i = tid; i < N; i += 256){
      unsigned int v = vals[i];
      if ((v & above) == p && (v & bit)) cnt++;
    }
    float cf = wredSum((float)cnt);
    if ((tid & 63) == 0) shc[tid >> 6] = cf;
    __syncthreads();
    if (tid == 0){
      int c1 = (int)(shc[0] + shc[1] + shc[2] + shc[3] + 0.5f);
      if (k_sh <= c1) p_sh = p | bit;
      else k_sh -= c1;
    }
    __syncthreads();
  }
  if (tid == 0) thr[blockIdx.x] = __uint_as_float(p_sh);
}

__global__ __launch_bounds__(256) void k_mask(const float* __restrict__ ax, const float* __restrict__ ay,
                                              const float* __restrict__ thr, float* __restrict__ mx,
                                              float* __restrict__ my){
  int j = blockIdx.x * 256 + threadIdx.x;
  mx[j] = (ax[j] >= thr[0] && ax[N + j] >= thr[1]) ? 1.f : 0.f;
  my[j] = (ay[j] >= thr[2] && ay[N + j] >= thr[3]) ? 1.f : 0.f;
}

// ======================= host =======================
extern "C" void kernel_launch(void* const* d_in, const int* in_sizes, int n_in,
                              void* d_out, int out_size, void* d_ws, size_t ws_size,
                              hipStream_t stream)
{
  const float* x     = (const float*)d_in[0];
  const float* y     = (const float*)d_in[1];
  const float* f_w   = (const float*)d_in[2];
  const float* f_b   = (const float*)d_in[3];
  const float* g_w   = (const float*)d_in[4];
  const float* g_b   = (const float*)d_in[5];
  const float* saf_w = (const float*)d_in[6];
  const float* saf_b = (const float*)d_in[7];
  const float* sag_w = (const float*)d_in[8];
  const float* sag_b = (const float*)d_in[9];
  const float* h_w   = (const float*)d_in[10];
  const float* h_b   = (const float*)d_in[11];
  const float* ow    = (const float*)d_in[12];
  const float* ob    = (const float*)d_in[13];

  const size_t MBy = 1ull << 20;
  char* base = (char*)d_ws;
  if (ws_size < 207 * MBy) return;
  auto F  = [&](size_t off){ return (float*)(base + off); };
  auto Bp = [&](size_t off){ return (__bf16*)(base + off); };

  // region EN [0,64MB): prep-phase xa/ya/fc pairs -> NS-refine fp32 -> energy fp32
  __bf16 *xaH = Bp(0), *xaL = Bp(8*MBy), *yaH = Bp(16*MBy), *yaL = Bp(24*MBy);
  __bf16 *fcH = Bp(32*MBy), *fcL = Bp(48*MBy);       // [4][N][C]
  float  *Zf = F(0), *S1 = F(4*MBy), *TT = F(8*MBy), *Zf2 = F(12*MBy);
  float  *energy = F(0);                              // [N][N]
  // region [64,96MB): xz pair -> corr_h
  __bf16 *xzH = Bp(64*MBy), *xzL = Bp(80*MBy);        // [4][N][C]
  __bf16 *corrH = Bp(64*MBy);
  // region [96,128MB): sabuf + NS mats -> corr_l
  __bf16 *fsaH = Bp(96*MBy), *fsaL = Bp(100*MBy), *gsaH = Bp(104*MBy), *gsaL = Bp(108*MBy);
  __bf16 *Y0h = Bp(112*MBy), *Y0l = Bp(114*MBy), *Z0h = Bp(116*MBy), *Z0l = Bp(118*MBy);
  __bf16 *Y1h = Bp(120*MBy), *Y1l = Bp(122*MBy), *Z1h = Bp(124*MBy), *Z1l = Bp(126*MBy);
  __bf16 *corrL = Bp(96*MBy);
  // region [128,160MB): main f/g pairs
  __bf16 *fpmH = Bp(128*MBy), *fpmL = Bp(136*MBy), *gpmH = Bp(144*MBy), *gpmL = Bp(152*MBy);
  // region [160,176MB): y_pm -> res
  __bf16 *ypmH = Bp(160*MBy), *ypmL = Bp(168*MBy);
  __bf16 *resH = ypmH, *resL = ypmL;
  // region [176,192MB): h pair
  __bf16 *hH = Bp(176*MBy), *hL = Bp(184*MBy);
  // [192,196MB): Tm pair / refined-Z pair
  __bf16 *tmH = Bp(192*MBy), *tmL = Bp(194*MBy);
  float *covb = F(196*MBy);                           // [4][C][C]
  // weights [200,206MB)
  __bf16 *fwH = Bp(200*MBy), *fwL = Bp(200*MBy + 512*1024);
  __bf16 *gwH = Bp(201*MBy), *gwL = Bp(201*MBy + 512*1024);
  __bf16 *sfH = Bp(202*MBy), *sfL = Bp(202*MBy + 512*1024);
  __bf16 *sgH = Bp(203*MBy), *sgL = Bp(203*MBy + 512*1024);
  __bf16 *hwH = Bp(204*MBy), *hwL = Bp(204*MBy + 512*1024);
  __bf16 *owH = Bp(205*MBy), *owL = Bp(205*MBy + 512*1024);
  // small [206,207MB)
  float *meanv = F(206*MBy);
  float *invs  = F(206*MBy + 8*1024);
  float *rm    = F(206*MBy + 16*1024);
  float *rsc   = F(206*MBy + 32*1024);
  float *mxv   = F(206*MBy + 48*1024);
  float *myv   = F(206*MBy + 64*1024);
  float *thr   = F(206*MBy + 80*1024);
  float *invt  = F(206*MBy + 80*1024 + 256);
  float *invsqt= F(206*MBy + 80*1024 + 512);
  unsigned int *tbits = (unsigned int*)(base + 206*MBy + 80*1024 + 768);
  float *partials = F(206*MBy + 128*1024);            // [32][N]

  float* outm = (float*)d_out;               // [2][C][N]
  float* attx = outm + B2 * CN;              // [2][N]
  float* atty = attx + (long)B2 * N;

  // 1) stats + pixel-major prep
  k_stats<<<dim3(4 * C), dim3(256), 0, stream>>>(x, y, meanv, invs);
  k_prep<<<dim3(64, 8, 2), dim3(256), 0, stream>>>(x, meanv, invs, 0, xaH, xaL, fcH, fcL, nullptr, nullptr);
  k_prep<<<dim3(64, 8, 2), dim3(256), 0, stream>>>(y, meanv, invs, 2, yaH, yaL, fcH + 2*NC, fcL + 2*NC, ypmH, ypmL);

  // 2) weight conversions
  {
    const int nb = (int)(CC / 256);
    k_wcvt<<<nb, 256, 0, stream>>>(f_w, fwH, fwL, (int)CC);
    k_wcvt<<<nb, 256, 0, stream>>>(g_w, gwH, gwL, (int)CC);
    k_wcvt<<<nb, 256, 0, stream>>>(saf_w, sfH, sfL, (int)CC);
    k_wcvt<<<nb, 256, 0, stream>>>(sag_w, sgH, sgL, (int)CC);
    k_wcvt<<<nb, 256, 0, stream>>>(h_w, hwH, hwL, (int)CC);
    k_wcvt<<<nb, 256, 0, stream>>>(ow, owH, owL, (int)CC);
  }

  // 3) cov = x x^T /(n-1)  (fp32), finish subtracts mean term, adds 2eps*I, Gershgorin
  k_gemm<0,1,0><<<dim3(8, 8, 2), dim3(256), 0, stream>>>(x, x, covb,            C, C, N, CN, CN, CC, 1.f/(float)(N-1), nullptr, nullptr, nullptr, 0);
  k_gemm<0,1,0><<<dim3(8, 8, 2), dim3(256), 0, stream>>>(y, y, covb + 2*CC,     C, C, N, CN, CN, CC, 1.f/(float)(N-1), nullptr, nullptr, nullptr, 0);
  hipMemsetAsync(tbits, 0, 4 * sizeof(unsigned int), stream);
  k_cov_finish<<<dim3(C, 4), dim3(128), 0, stream>>>(covb, meanv, tbits);
  k_scalars<<<dim3(1), dim3(8), 0, stream>>>(tbits, invt, invsqt);

  // 4) main convs (xa/ya/y_pm consumed; frees EN lower half for NS refine)
  mm<0,1>(stream, xaH, xaL, fwH, fwL, nullptr, fpmH, fpmL, N, C, C, NC, 0, NC, 2, 1.f, nullptr, nullptr, f_b, nullptr, 0);
  mm<0,1>(stream, yaH, yaL, gwH, gwL, nullptr, gpmH, gpmL, N, C, C, NC, 0, NC, 2, 1.f, nullptr, nullptr, g_b, nullptr, 0);
  mm<0,1>(stream, hwH, hwL, ypmH, ypmL, nullptr, hH, hL, C, N, C, 0, NC, CN, 2, 1.f, nullptr, h_b, nullptr, nullptr, 0);

  // 5) Newton-Schulz in split-bf16
  k_ns_init<<<dim3(C, 4), dim3(256), 0, stream>>>(covb, invt, Y0h, Y0l, Z0h, Z0l);
  __bf16 *Ych = Y0h, *Ycl = Y0l, *Zch = Z0h, *Zcl = Z0l;
  __bf16 *Ynh = Y1h, *Ynl = Y1l, *Znh = Z1h, *Znl = Z1l;
  for (int it = 0; it < NS_ITERS; ++it){
    mm<1,1>(stream, Zch, Zcl, Ych, Ycl, nullptr, tmH, tmL, C, C, C, CC, CC, CC, 4, 1.f, nullptr, nullptr, nullptr, nullptr, 0);
    mm<0,1>(stream, Ych, Ycl, tmH, tmL, nullptr, Ynh, Ynl, C, C, C, CC, CC, CC, 4, 1.f, nullptr, nullptr, nullptr, nullptr, 0);
    mm<0,1>(stream, tmH, tmL, Zch, Zcl, nullptr, Znh, Znl, C, C, C, CC, CC, CC, 4, 1.f, nullptr, nullptr, nullptr, nullptr, 0);
    __bf16* t;
    t = Ych; Ych = Ynh; Ynh = t;  t = Ycl; Ycl = Ynl; Ynl = t;
    t = Zch; Zch = Znh; Znh = t;  t = Zcl; Zcl = Znl; Znl = t;
  }
  // 5b) one fp32 Newton polish: Z' = Z(3I - (cov/t) Z^2)/2
  k_pair2f<<<dim3((int)(4*CC/256)), 256, 0, stream>>>(Zch, Zcl, Zf, (int)(4*CC));
  k_gemm<0,0,0><<<dim3(8, 8, 4), dim3(256), 0, stream>>>(Zf, Zf, S1, C, C, C, CC, CC, CC, 1.f, nullptr, nullptr, nullptr, 0);
  k_gemm<0,0,1><<<dim3(8, 8, 4), dim3(256), 0, stream>>>(covb, S1, TT, C, C, C, CC, CC, CC, 1.f, invt, nullptr, nullptr, 0);
  k_gemm<0,0,0><<<dim3(8, 8, 4), dim3(256), 0, stream>>>(Zf, TT, Zf2, C, C, C, CC, CC, CC, 1.f, nullptr, nullptr, nullptr, 0);
  k_wcvt<<<dim3((int)(4*CC/256)), 256, 0, stream>>>(Zf2, tmH, tmL, (int)(4*CC));

  // 6) zca apply: xz_pm = (1/sqrt(t)) fc_pm . Z
  mm<0,1>(stream, fcH, fcL, tmH, tmL, nullptr, xzH, xzL, N, C, C, NC, CC, NC, 4, 1.f, invsqt, nullptr, nullptr, nullptr, 0);

  // 7) self-attention blocks -> atten  (energy overwrites EN region; fc/xa dead)
  for (int t2 = 0; t2 < 2; ++t2){
    for (int b = 0; b < B2; ++b){
      const int z = t2 * 2 + b;
      mm<0,1>(stream, xzH + (long)z*NC, xzL + (long)z*NC, sfH, sfL, nullptr, fsaH, fsaL, N, C, C, 0, 0, 0, 1, 1.f, nullptr, nullptr, saf_b, nullptr, 0);
      mm<0,1>(stream, xzH + (long)z*NC, xzL + (long)z*NC, sgH, sgL, nullptr, gsaH, gsaL, N, C, C, 0, 0, 0, 1, 1.f, nullptr, nullptr, sag_b, nullptr, 0);
      mm<0,0>(stream, fsaH, fsaL, gsaH, gsaL, energy, nullptr, nullptr, N, N, C, 0, 0, 0, 1, 1.f, nullptr, nullptr, nullptr, nullptr, 0);
      k_rowstats<0><<<dim3(N), dim3(256), 0, stream>>>(energy, nullptr, nullptr, rm, rsc);
      k_colaccum<<<dim3(16, 32), dim3(256), 0, stream>>>(energy, rm, rsc, partials);
      k_colreduce<<<dim3(16), dim3(256), 0, stream>>>(partials, (t2 == 0 ? attx : atty) + (long)b * N);
    }
  }

  // 8) masks
  k_radix<<<dim3(2), dim3(256), 0, stream>>>(attx, thr);
  k_radix<<<dim3(2), dim3(256), 0, stream>>>(atty, thr + 2);
  k_mask<<<dim3(16), dim3(256), 0, stream>>>(attx, atty, thr, mxv, myv);

  // 9) main path per batch
  for (int b = 0; b < B2; ++b){
    mm<0,0>(stream, fpmH + (long)b*NC, fpmL + (long)b*NC, gpmH + (long)b*NC, gpmL + (long)b*NC,
            energy, nullptr, nullptr, N, N, C, 0, 0, 0, 1, 1.f, nullptr, nullptr, nullptr, nullptr, 0);
    k_rowstats<1><<<dim3(N), dim3(256), 0, stream>>>(energy, mxv, myv, rm, rsc);
    k_wmask<<<dim3(N, 16), dim3(256), 0, stream>>>(energy, mxv, myv, rm, rsc, corrH, corrL);
    mm<0,1>(stream, corrH, corrL, hH + (long)b*CN, hL + (long)b*CN, nullptr, resH, resL,
            N, C, N, 0, 0, 0, 1, 1.f, nullptr, nullptr, nullptr, nullptr, 0);
    mm<0,0>(stream, owH, owL, resH, resL, outm + (long)b*CN, nullptr, nullptr,
            C, N, C, 0, 0, 0, 1, 1.f, nullptr, ob, nullptr, x + (long)b*CN, 0);
  }
}

// Round 3
// 1652.881 us; speedup vs baseline: 3.2119x; 1.8128x over previous
//
#include <hip/hip_runtime.h>
#include <cstdint>

static constexpr int B2 = 2;
static constexpr int C = 512;
static constexpr int N = 4096;
static constexpr long CN = (long)C * N;
static constexpr long NC = (long)N * C;
static constexpr long CC = (long)C * C;
static constexpr float EPSC = 1e-5f;
static constexpr int KSEL = 308;       // N - int(N*0.925)
static constexpr int NS_ITERS = 10;

typedef __attribute__((ext_vector_type(8))) __bf16 bf16x8;
typedef __attribute__((ext_vector_type(4))) float f32x4;

__device__ __forceinline__ float wredSum(float v){
#pragma unroll
  for (int o = 32; o >= 1; o >>= 1) v += __shfl_xor(v, o, 64);
  return v;
}
__device__ __forceinline__ float wredMax(float v){
#pragma unroll
  for (int o = 32; o >= 1; o >>= 1) v = fmaxf(v, __shfl_xor(v, o, 64));
  return v;
}

__device__ __forceinline__ void gld16(const __bf16* g, __bf16* l){
  __builtin_amdgcn_global_load_lds(
      (const __attribute__((address_space(1))) void*)g,
      (__attribute__((address_space(3))) void*)l, 16, 0, 0);
}

__device__ __forceinline__ void splitw(float v, __bf16* ph, __bf16* pl, long o){
  __bf16 h = (__bf16)v;
  ph[o] = h;
  pl[o] = (__bf16)(v - (float)h);
}

// ======================= split/plain bf16 MFMA GEMM, 128x128 tile, BK=32 =======================
// C[i,j] = alpha * sum_k A[i,k]*B[j,k]  (A:[M,K], B:[Nn,K] row-major; PASSES=3 -> hh+hl+lh)
// OUTMODE: 0 fp32, 1 bf16 pair, 2 bf16 high only
template<int PASSES, int TMH, int OUTMODE>
__global__ __launch_bounds__(256) void k_mm(
    const __bf16* __restrict__ Ah, const __bf16* __restrict__ Al,
    const __bf16* __restrict__ Bh, const __bf16* __restrict__ Bl,
    float* __restrict__ Cf, __bf16* __restrict__ Coh, __bf16* __restrict__ Col,
    int Nn, int K, long sAz, long sBz, long sCz,
    float alpha, const float* __restrict__ alpha_ptr,
    const float* __restrict__ bias_row, const float* __restrict__ bias_col,
    const float* __restrict__ addsrc, long sAddz)
{
  constexpr int NB = (PASSES == 3) ? 4 : 2;
  constexpr int SB = (PASSES == 3) ? 2 : 1;
  __shared__ __align__(16) __bf16 sm[NB][128 * 32];
  const int z = blockIdx.z;
  const int i0 = blockIdx.x * 128;
  const int j0 = blockIdx.y * 128;
  const int tid = threadIdx.x;
  const int lane = tid & 63;
  const int w = tid >> 6;
  const int wr = (w >> 1) * 64, wc = (w & 1) * 64;
  const int lr = lane & 15;
  const int g = lane >> 4;

  const __bf16* pAh = Ah + (long)z * sAz + (long)i0 * K;
  const __bf16* pBh = Bh + (long)z * sBz + (long)j0 * K;
  const __bf16* pAl = (PASSES == 3) ? (Al + (long)z * sAz + (long)i0 * K) : nullptr;
  const __bf16* pBl = (PASSES == 3) ? (Bl + (long)z * sBz + (long)j0 * K) : nullptr;

  f32x4 acc[4][4] = {};

  for (int kt = 0; kt < K; kt += 32){
#pragma unroll
    for (int p = 0; p < 2; ++p){
      const int t2 = p * 256 + tid;
      const int row = t2 >> 2;
      const int gs = (t2 & 3) ^ ((row >> 1) & 3);
      const long go = (long)row * K + kt + gs * 8;
      gld16(pAh + go, &sm[0][t2 * 8]);
      gld16(pBh + go, &sm[SB][t2 * 8]);
      if constexpr (PASSES == 3){
        gld16(pAl + go, &sm[1][t2 * 8]);
        gld16(pBl + go, &sm[3][t2 * 8]);
      }
    }
    __syncthreads();
    bf16x8 fa[4], fal[4], fb[4], fbl[4];
#pragma unroll
    for (int mi = 0; mi < 4; ++mi){
      const int row = wr + mi * 16 + lr;
      const int off = row * 32 + ((g ^ ((row >> 1) & 3)) * 8);
      fa[mi] = *(const bf16x8*)(&sm[0][off]);
      if constexpr (PASSES == 3) fal[mi] = *(const bf16x8*)(&sm[1][off]);
    }
#pragma unroll
    for (int ni = 0; ni < 4; ++ni){
      const int row = wc + ni * 16 + lr;
      const int off = row * 32 + ((g ^ ((row >> 1) & 3)) * 8);
      fb[ni] = *(const bf16x8*)(&sm[SB][off]);
      if constexpr (PASSES == 3) fbl[ni] = *(const bf16x8*)(&sm[3][off]);
    }
#pragma unroll
    for (int mi = 0; mi < 4; ++mi)
#pragma unroll
      for (int ni = 0; ni < 4; ++ni){
        acc[mi][ni] = __builtin_amdgcn_mfma_f32_16x16x32_bf16(fa[mi], fb[ni], acc[mi][ni], 0, 0, 0);
        if constexpr (PASSES == 3){
          acc[mi][ni] = __builtin_amdgcn_mfma_f32_16x16x32_bf16(fa[mi],  fbl[ni], acc[mi][ni], 0, 0, 0);
          acc[mi][ni] = __builtin_amdgcn_mfma_f32_16x16x32_bf16(fal[mi], fb[ni],  acc[mi][ni], 0, 0, 0);
        }
      }
    __syncthreads();
  }

  float al2 = alpha;
  if (alpha_ptr) al2 *= alpha_ptr[z];
#pragma unroll
  for (int mi = 0; mi < 4; ++mi){
#pragma unroll
    for (int ni = 0; ni < 4; ++ni){
      const int col = j0 + wc + ni * 16 + lr;
      const float bc = bias_col ? bias_col[col] : 0.f;
#pragma unroll
      for (int j = 0; j < 4; ++j){
        const int row = i0 + wr + mi * 16 + g * 4 + j;
        float v = acc[mi][ni][j] * al2;
        if (TMH) v = (((row == col) ? 3.f : 0.f) - v) * 0.5f;
        if (bias_row) v += bias_row[row];
        v += bc;
        if (addsrc) v += addsrc[(long)z * sAddz + (long)row * Nn + col];
        const long o = (long)z * sCz + (long)row * Nn + col;
        if (OUTMODE == 0){ Cf[o] = v; }
        else if (OUTMODE == 1){ __bf16 h = (__bf16)v; Coh[o] = h; Col[o] = (__bf16)(v - (float)h); }
        else { Coh[o] = (__bf16)v; }
      }
    }
  }
}

// ======================= split-bf16 MFMA GEMM, 64x64 tile, BK=64 (always 3-pass) =======================
// NSYZ=1: z<4 -> out.Y[z] = A.Y[z]*A.T[z]^T ; z>=4 -> out.Z[zz] = A.T[zz]*A.Z[zz]^T
template<int TMH, int OUTMODE, int NSYZ>
__global__ __launch_bounds__(256) void k_mm64(
    const __bf16* __restrict__ Ah, const __bf16* __restrict__ Al,
    const __bf16* __restrict__ Bh, const __bf16* __restrict__ Bl,
    float* __restrict__ Cf, __bf16* __restrict__ Coh, __bf16* __restrict__ Col,
    int Nn, int K, long sAz, long sBz, long sCz, float alpha)
{
  __shared__ __align__(16) __bf16 sm[4][64 * 64];
  const int z = blockIdx.z;
  long oA, oB, oC;
  if (NSYZ){
    if (z < 4){ oA = (long)z * CC; oB = (long)(4 + z) * CC; oC = (long)z * CC; }
    else { int zz = z - 4; oA = (long)(4 + zz) * CC; oB = (long)(8 + zz) * CC; oC = (long)(8 + zz) * CC; }
  } else {
    oA = (long)z * sAz; oB = (long)z * sBz; oC = (long)z * sCz;
  }
  const int i0 = blockIdx.x * 64;
  const int j0 = blockIdx.y * 64;
  const int tid = threadIdx.x;
  const int lane = tid & 63;
  const int w = tid >> 6;
  const int wr = (w >> 1) * 32, wc = (w & 1) * 32;
  const int lr = lane & 15;
  const int g = lane >> 4;

  const __bf16* pAh = Ah + oA + (long)i0 * K;
  const __bf16* pAl = Al + oA + (long)i0 * K;
  const __bf16* pBh = Bh + oB + (long)j0 * K;
  const __bf16* pBl = Bl + oB + (long)j0 * K;

  f32x4 acc[2][2] = {};

  for (int kt = 0; kt < K; kt += 64){
#pragma unroll
    for (int p = 0; p < 2; ++p){
      const int t2 = p * 256 + tid;
      const int row = t2 >> 3;
      const int gs = (t2 & 7) ^ (row & 7);
      const long go = (long)row * K + kt + gs * 8;
      gld16(pAh + go, &sm[0][t2 * 8]);
      gld16(pAl + go, &sm[1][t2 * 8]);
      gld16(pBh + go, &sm[2][t2 * 8]);
      gld16(pBl + go, &sm[3][t2 * 8]);
    }
    __syncthreads();
#pragma unroll
    for (int ks = 0; ks < 2; ++ks){
      bf16x8 fa[2], fal[2], fb[2], fbl[2];
#pragma unroll
      for (int mi = 0; mi < 2; ++mi){
        const int row = wr + mi * 16 + lr;
        const int off = row * 64 + (((ks * 4 + g) ^ (row & 7)) * 8);
        fa[mi]  = *(const bf16x8*)(&sm[0][off]);
        fal[mi] = *(const bf16x8*)(&sm[1][off]);
      }
#pragma unroll
      for (int ni = 0; ni < 2; ++ni){
        const int row = wc + ni * 16 + lr;
        const int off = row * 64 + (((ks * 4 + g) ^ (row & 7)) * 8);
        fb[ni]  = *(const bf16x8*)(&sm[2][off]);
        fbl[ni] = *(const bf16x8*)(&sm[3][off]);
      }
#pragma unroll
      for (int mi = 0; mi < 2; ++mi)
#pragma unroll
        for (int ni = 0; ni < 2; ++ni){
          acc[mi][ni] = __builtin_amdgcn_mfma_f32_16x16x32_bf16(fa[mi],  fb[ni],  acc[mi][ni], 0, 0, 0);
          acc[mi][ni] = __builtin_amdgcn_mfma_f32_16x16x32_bf16(fa[mi],  fbl[ni], acc[mi][ni], 0, 0, 0);
          acc[mi][ni] = __builtin_amdgcn_mfma_f32_16x16x32_bf16(fal[mi], fb[ni],  acc[mi][ni], 0, 0, 0);
        }
    }
    __syncthreads();
  }

#pragma unroll
  for (int mi = 0; mi < 2; ++mi){
#pragma unroll
    for (int ni = 0; ni < 2; ++ni){
      const int col = j0 + wc + ni * 16 + lr;
#pragma unroll
      for (int j = 0; j < 4; ++j){
        const int row = i0 + wr + mi * 16 + g * 4 + j;
        float v = acc[mi][ni][j] * alpha;
        if (TMH) v = (((row == col) ? 3.f : 0.f) - v) * 0.5f;
        const long o = oC + (long)row * Nn + col;
        if (OUTMODE == 0){ Cf[o] = v; }
        else { __bf16 h = (__bf16)v; Coh[o] = h; Col[o] = (__bf16)(v - (float)h); }
      }
    }
  }
}

// ======================= fp32 GEMM (polish only; validated round-1/2) =======================
template<int TRA, int TRB, int TMH>
__global__ __launch_bounds__(256) void k_gemm(
    const float* __restrict__ A, const float* __restrict__ B, float* __restrict__ Co,
    int M, int Nn, int K, long sA, long sB, long sC,
    float alpha, const float* __restrict__ alpha_ptr,
    const float* __restrict__ bias,
    const float* __restrict__ addsrc, long sAdd)
{
  __shared__ __align__(16) float As[16][68];
  __shared__ __align__(16) float Bs[16][68];
  const int z = blockIdx.z;
  const float* Ab = A + (long)z * sA;
  const float* Bb = B + (long)z * sB;
  float* Cb = Co + (long)z * sC;
  const int i0 = blockIdx.x * 64;
  const int j0 = blockIdx.y * 64;
  const int tid = threadIdx.x;
  float acc[4][4] = {{0.f}};
  for (int kt = 0; kt < K; kt += 16){
#pragma unroll
    for (int p = 0; p < 4; ++p){
      int idx = tid + p * 256;
      if (TRA == 0){
        int i = idx >> 4, kk = idx & 15;
        As[kk][i] = Ab[(long)(i0 + i) * K + (kt + kk)];
      } else {
        int kk = idx >> 6, i = idx & 63;
        As[kk][i] = Ab[(long)(kt + kk) * M + (i0 + i)];
      }
      if (TRB == 0){
        int kk = idx >> 6, j = idx & 63;
        Bs[kk][j] = Bb[(long)(kt + kk) * Nn + (j0 + j)];
      } else {
        int j = idx >> 4, kk = idx & 15;
        Bs[kk][j] = Bb[(long)(j0 + j) * K + (kt + kk)];
      }
    }
    __syncthreads();
    const int ty = tid >> 4, tx = tid & 15;
#pragma unroll
    for (int kk = 0; kk < 16; ++kk){
      const float4 av = *reinterpret_cast<const float4*>(&As[kk][ty * 4]);
      const float4 bv = *reinterpret_cast<const float4*>(&Bs[kk][tx * 4]);
      float aa[4] = {av.x, av.y, av.z, av.w};
      float bb[4] = {bv.x, bv.y, bv.z, bv.w};
#pragma unroll
      for (int r = 0; r < 4; ++r)
#pragma unroll
        for (int c2 = 0; c2 < 4; ++c2)
          acc[r][c2] = fmaf(aa[r], bb[c2], acc[r][c2]);
    }
    __syncthreads();
  }
  const int ty = tid >> 4, tx = tid & 15;
  float al = alpha;
  if (alpha_ptr) al *= alpha_ptr[z];
#pragma unroll
  for (int r = 0; r < 4; ++r){
    const int gi = i0 + ty * 4 + r;
    const float bval = bias ? bias[gi] : 0.f;
#pragma unroll
    for (int c2 = 0; c2 < 4; ++c2){
      const int gj = j0 + tx * 4 + c2;
      float v = acc[r][c2] * al;
      if (TMH) v = (((gi == gj) ? 3.f : 0.f) - v) * 0.5f;
      v += bval;
      if (addsrc) v += addsrc[(long)z * sAdd + (long)gi * Nn + gj];
      Cb[(long)gi * Nn + gj] = v;
    }
  }
}

// ======================= prep / stats =======================
__global__ __launch_bounds__(256) void k_stats(const float* __restrict__ x, const float* __restrict__ y,
                                               float* __restrict__ meanv, float* __restrict__ invs){
  const int bid = blockIdx.x;           // 0..4*C-1
  const int t = bid >> 9, c = bid & 511;
  const float* src = (t < 2 ? x : y) + (long)(t & 1) * CN + (long)c * N;
  const int tid = threadIdx.x;
  float s1 = 0.f, s2 = 0.f;
  for (int i = tid; i < N; i += 256){ float v = src[i]; s1 += v; s2 += v * v; }
  __shared__ float sh1[4], sh2[4];
  s1 = wredSum(s1); s2 = wredSum(s2);
  if ((tid & 63) == 0){ sh1[tid >> 6] = s1; sh2[tid >> 6] = s2; }
  __syncthreads();
  if (tid == 0){
    float m = (sh1[0] + sh1[1] + sh1[2] + sh1[3]) * (1.f / (float)N);
    float ex2 = (sh2[0] + sh2[1] + sh2[2] + sh2[3]) * (1.f / (float)N);
    float var = ex2 - m * m;
    meanv[t * C + c] = m;
    invs[t * C + c] = rsqrtf((var > 0.f ? var : 0.f) + EPSC);
  }
}

// per-call: transpose [C,N] fp32 -> pixel-major outputs; also channel-major centered pairs
__global__ __launch_bounds__(256) void k_prep(const float* __restrict__ src,
                                              const float* __restrict__ meanv, const float* __restrict__ invs, int toff,
                                              __bf16* __restrict__ adH,
                                              __bf16* __restrict__ fcH, __bf16* __restrict__ fcL,
                                              __bf16* __restrict__ ccH, __bf16* __restrict__ ccL,
                                              __bf16* __restrict__ rwH){
  __shared__ float tile[64][65];
  const int z = blockIdx.z;
  const int n0 = blockIdx.x * 64;
  const int c0 = blockIdx.y * 64;
  const int tid = threadIdx.x;
  const int tx = tid & 63, ty = tid >> 6;
  const int tgt = toff + z;
#pragma unroll
  for (int it = 0; it < 16; ++it){
    const int cc = it * 4 + ty;
    const float v = src[(long)z * CN + (long)(c0 + cc) * N + n0 + tx];
    tile[cc][tx] = v;
    const float cen = v - meanv[tgt * C + c0 + cc];
    const long oc = (long)tgt * CN + (long)(c0 + cc) * N + n0 + tx;
    splitw(cen, ccH, ccL, oc);
  }
  __syncthreads();
  const float m = meanv[tgt * C + c0 + tx];
  const float r = invs[tgt * C + c0 + tx];
#pragma unroll
  for (int it = 0; it < 16; ++it){
    const int p = it * 4 + ty;
    const float v = tile[tx][p];
    const float cen = v - m;
    const long o = (long)z * NC + (long)(n0 + p) * C + c0 + tx;
    adH[o] = (__bf16)(cen * r);
    const long o4 = (long)tgt * NC + (long)(n0 + p) * C + c0 + tx;
    splitw(cen, fcH, fcL, o4);
    if (rwH) rwH[o] = (__bf16)v;
  }
}

__global__ __launch_bounds__(256) void k_wcvt(const float* __restrict__ s, __bf16* __restrict__ h,
                                              __bf16* __restrict__ l, int n){
  int i = blockIdx.x * 256 + threadIdx.x;
  if (i < n) splitw(s[i], h, l, i);
}

__global__ __launch_bounds__(256) void k_wcvt_h(const float* __restrict__ s, __bf16* __restrict__ h, int n){
  int i = blockIdx.x * 256 + threadIdx.x;
  if (i < n) h[i] = (__bf16)s[i];
}

__global__ __launch_bounds__(256) void k_pair2f(const __bf16* __restrict__ h, const __bf16* __restrict__ l,
                                                float* __restrict__ o, int n){
  int i = blockIdx.x * 256 + threadIdx.x;
  if (i < n) o[i] = (float)h[i] + (float)l[i];
}

// ======================= cov finish / NS init =======================
__global__ __launch_bounds__(128) void k_cov_finish(float* __restrict__ cov, unsigned int* __restrict__ tbits){
  const int r = blockIdx.x, z = blockIdx.y;
  float* row = cov + (long)z * CC + (long)r * C;
  const int tid = threadIdx.x;
  float s = 0.f;
  for (int i = tid; i < C; i += 128){
    float v = row[i];
    if (i == r){ v += 2.f * EPSC; row[i] = v; }
    s += fabsf(v);
  }
  s = wredSum(s);
  __shared__ float sh[2];
  if ((tid & 63) == 0) sh[tid >> 6] = s;
  __syncthreads();
  if (tid == 0) atomicMax(tbits + z, __float_as_uint(sh[0] + sh[1]));
}

__global__ void k_scalars(const unsigned int* __restrict__ tbits, float* __restrict__ invt, float* __restrict__ invsqt){
  int z = threadIdx.x;
  if (z < 4){
    float t = __uint_as_float(tbits[z]);
    invt[z] = 1.f / t;
    invsqt[z] = rsqrtf(t);
  }
}

// writes Y (planes 0..3) and Z=I (planes 8..11) of the packed NS buffer [Y|T|Z]
__global__ __launch_bounds__(256) void k_ns_init(const float* __restrict__ cov, const float* __restrict__ invt,
                                                 __bf16* __restrict__ h, __bf16* __restrict__ l){
  const int r = blockIdx.x, z = blockIdx.y;
  const long base = (long)z * CC + (long)r * C;
  const float it = invt[z];
  for (int i = threadIdx.x; i < C; i += 256){
    splitw(cov[base + i] * it, h, l, base + i);
    h[8 * CC + base + i] = (__bf16)((i == r) ? 1.f : 0.f);
    l[8 * CC + base + i] = (__bf16)0.f;
  }
}

// ======================= softmax aux (vectorized) =======================
template<int MASKED>
__global__ __launch_bounds__(256) void k_rowstats(
    const float* __restrict__ E, const float* __restrict__ mx, const float* __restrict__ my,
    float* __restrict__ rowmax, float* __restrict__ rowscale)
{
  const int row = blockIdx.x;
  const float* pe = E + (long)row * N;
  const int tid = threadIdx.x;
  __shared__ float sh[4], shb[4];
  float mv = -3.4e38f;
  for (int i = tid * 4; i < N; i += 1024){
    const float4 v = *reinterpret_cast<const float4*>(pe + i);
    mv = fmaxf(mv, fmaxf(fmaxf(v.x, v.y), fmaxf(v.z, v.w)));
  }
  mv = wredMax(mv);
  if ((tid & 63) == 0) sh[tid >> 6] = mv;
  __syncthreads();
  const float M_ = fmaxf(fmaxf(sh[0], sh[1]), fmaxf(sh[2], sh[3]));
  const float target = MASKED ? mx[row] : 0.f;
  float s = 0.f, smv = 0.f;
  for (int i = tid * 4; i < N; i += 1024){
    const float4 v = *reinterpret_cast<const float4*>(pe + i);
    float4 wv;
    if (MASKED) wv = *reinterpret_cast<const float4*>(my + i);
    const float e0 = __expf(v.x - M_), e1 = __expf(v.y - M_);
    const float e2 = __expf(v.z - M_), e3 = __expf(v.w - M_);
    s += (e0 + e1) + (e2 + e3);
    if (MASKED){
      if (wv.x == target) smv += e0;
      if (wv.y == target) smv += e1;
      if (wv.z == target) smv += e2;
      if (wv.w == target) smv += e3;
    }
  }
  __syncthreads();
  s = wredSum(s);
  if (MASKED) smv = wredSum(smv);
  if ((tid & 63) == 0){ sh[tid >> 6] = s; shb[tid >> 6] = smv; }
  __syncthreads();
  if (tid == 0){
    float S = sh[0] + sh[1] + sh[2] + sh[3];
    if (MASKED){
      float Sm = shb[0] + shb[1] + shb[2] + shb[3];
      float l1 = Sm / S;
      if (l1 < 1e-12f) l1 = 1e-12f;
      rowscale[row] = 1.f / (S * l1);
    } else {
      rowscale[row] = 1.f / S;
    }
    rowmax[row] = M_;
  }
}

__global__ __launch_bounds__(256) void k_wmask(
    const float* __restrict__ E, const float* __restrict__ mx, const float* __restrict__ my,
    const float* __restrict__ rowmax, const float* __restrict__ rowscale,
    __bf16* __restrict__ ch)
{
  const int row = blockIdx.x;
  const int j = (blockIdx.y * 256 + threadIdx.x) * 4;
  const float target = mx[row];
  const float rm = rowmax[row], rs = rowscale[row];
  const long idx = (long)row * N + j;
  const float4 e = *reinterpret_cast<const float4*>(E + idx);
  const float4 wv = *reinterpret_cast<const float4*>(my + j);
  union { __bf16 b[4]; uint2 u; } pk;
  pk.b[0] = (__bf16)((wv.x == target) ? __expf(e.x - rm) * rs : 0.f);
  pk.b[1] = (__bf16)((wv.y == target) ? __expf(e.y - rm) * rs : 0.f);
  pk.b[2] = (__bf16)((wv.z == target) ? __expf(e.z - rm) * rs : 0.f);
  pk.b[3] = (__bf16)((wv.w == target) ? __expf(e.w - rm) * rs : 0.f);
  *reinterpret_cast<uint2*>(ch + idx) = pk.u;
}

__global__ __launch_bounds__(256) void k_colaccum(const float* __restrict__ E, const float* __restrict__ rowmax,
                                                  const float* __restrict__ rowscale, float* __restrict__ partials){
  const int j = (blockIdx.x * 256 + threadIdx.x) * 4;
  const int r0 = blockIdx.y * 128;
  float4 acc = {0.f, 0.f, 0.f, 0.f};
  for (int r2 = r0; r2 < r0 + 128; ++r2){
    const float4 e = *reinterpret_cast<const float4*>(E + (long)r2 * N + j);
    const float rm = rowmax[r2], rs = rowscale[r2];
    acc.x += __expf(e.x - rm) * rs;
    acc.y += __expf(e.y - rm) * rs;
    acc.z += __expf(e.z - rm) * rs;
    acc.w += __expf(e.w - rm) * rs;
  }
  *reinterpret_cast<float4*>(partials + (long)blockIdx.y * N + j) = acc;
}

__global__ __launch_bounds__(256) void k_colreduce(const float* __restrict__ partials, float* __restrict__ att){
  const int j = blockIdx.x * 256 + threadIdx.x;
  float s = 0.f;
  for (int c2 = 0; c2 < 32; ++c2) s += partials[(long)c2 * N + j];
  att[j] = s * (1.f / (float)N);
}

// ======================= mask (radix select) =======================
__global__ __launch_bounds__(256) void k_radix(const float* __restrict__ a, float* __restrict__ thr){
  __shared__ unsigned int vals[N];
  __shared__ float shc[4];
  __shared__ unsigned int p_sh;
  __shared__ int k_sh;
  const float* pa = a + (long)blockIdx.x * N;
  const int tid = threadIdx.x;
  for (int i = tid; i < N; i += 256) vals[i] = __float_as_uint(pa[i]);
  if (tid == 0){ p_sh = 0u; k_sh = KSEL; }
  __syncthreads();
  for (int b = 31; b >= 0; --b){
    const unsigned int bit = 1u << b;
    const unsigned int above = (b == 31) ? 0u : ~((bit << 1) - 1u);
    const unsigned int p = p_sh;
    int cnt = 0;
    for (int i = tid; i < N; i += 256){
      unsigned int v = vals[i];
      if ((v & above) == p && (v & bit)) cnt++;
    }
    float cf = wredSum((float)cnt);
    if ((tid & 63) == 0) shc[tid >> 6] = cf;
    __syncthreads();
    if (tid == 0){
      int c1 = (int)(shc[0] + shc[1] + shc[2] + shc[3] + 0.5f);
      if (k_sh <= c1) p_sh = p | bit;
      else k_sh -= c1;
    }
    __syncthreads();
  }
  if (tid == 0) thr[blockIdx.x] = __uint_as_float(p_sh);
}

__global__ __launch_bounds__(256) void k_mask(const float* __restrict__ ax, const float* __restrict__ ay,
                                              const float* __restrict__ thr, float* __restrict__ mx,
                                              float* __restrict__ my){
  int j = blockIdx.x * 256 + threadIdx.x;
  mx[j] = (ax[j] >= thr[0] && ax[N + j] >= thr[1]) ? 1.f : 0.f;
  my[j] = (ay[j] >= thr[2] && ay[N + j] >= thr[3]) ? 1.f : 0.f;
}

// ======================= host =======================
extern "C" void kernel_launch(void* const* d_in, const int* in_sizes, int n_in,
                              void* d_out, int out_size, void* d_ws, size_t ws_size,
                              hipStream_t stream)
{
  const float* x     = (const float*)d_in[0];
  const float* y     = (const float*)d_in[1];
  const float* f_w   = (const float*)d_in[2];
  const float* f_b   = (const float*)d_in[3];
  const float* g_w   = (const float*)d_in[4];
  const float* g_b   = (const float*)d_in[5];
  const float* saf_w = (const float*)d_in[6];
  const float* saf_b = (const float*)d_in[7];
  const float* sag_w = (const float*)d_in[8];
  const float* sag_b = (const float*)d_in[9];
  const float* h_w   = (const float*)d_in[10];
  const float* h_b   = (const float*)d_in[11];
  const float* ow    = (const float*)d_in[12];
  const float* ob    = (const float*)d_in[13];

  const size_t MBy = 1ull << 20;
  char* base = (char*)d_ws;
  if (ws_size < 205 * MBy) return;
  auto F  = [&](size_t off){ return (float*)(base + off); };
  auto Bp = [&](size_t off){ return (__bf16*)(base + off); };

  // [0,64MB): xaH, yaH, fc pairs  -> later energy fp32 [N][N]
  __bf16 *xaH = Bp(0), *yaH = Bp(8*MBy);
  __bf16 *fcH = Bp(16*MBy), *fcL = Bp(32*MBy);        // [4][N][C]
  float  *energy = F(0);
  // [64,96MB): xz pairs -> later corrH
  __bf16 *xzH = Bp(64*MBy), *xzL = Bp(80*MBy);        // [4][N][C]
  __bf16 *corrH = Bp(64*MBy);                         // [N][N] bf16
  // [96,112MB): self-attn conv outputs (pairs)
  __bf16 *fsaH = Bp(96*MBy), *fsaL = Bp(100*MBy), *gsaH = Bp(104*MBy), *gsaL = Bp(108*MBy);
  // [112,136MB): NS ping-pong buffers, each packed [Y(4)|T(4)|Z(4)] planes of CC
  __bf16 *nsAh = Bp(112*MBy), *nsAl = Bp(118*MBy), *nsBh = Bp(124*MBy), *nsBl = Bp(130*MBy);
  // [136,168MB): cc pairs (channel-major centered) -> later fpmH,gpmH,hH,resH
  __bf16 *ccH = Bp(136*MBy), *ccL = Bp(152*MBy);      // [4][C][N]
  __bf16 *fpmH = Bp(136*MBy), *gpmH = Bp(144*MBy);    // [2][N][C]
  __bf16 *hH = Bp(152*MBy);                           // [2][C][N]
  __bf16 *resH = Bp(160*MBy);                         // [N][C] per batch
  // [168,172MB): covb fp32 [4][C][C]
  float *covb = F(168*MBy);
  // weights
  __bf16 *fwH = Bp(172*MBy), *gwH = Bp(172*MBy + 512*1024);
  __bf16 *hwH = Bp(173*MBy), *owH = Bp(173*MBy + 512*1024);
  __bf16 *sfH = Bp(174*MBy), *sfL = Bp(174*MBy + 512*1024);
  __bf16 *sgH = Bp(175*MBy), *sgL = Bp(175*MBy + 512*1024);
  // smalls
  float *meanv = F(176*MBy);
  float *invs  = F(176*MBy + 8*1024);
  float *rm    = F(176*MBy + 16*1024);
  float *rsc   = F(176*MBy + 32*1024);
  float *mxv   = F(176*MBy + 48*1024);
  float *myv   = F(176*MBy + 64*1024);
  float *thr   = F(176*MBy + 80*1024);
  float *invt  = F(176*MBy + 80*1024 + 64);
  float *invsqt= F(176*MBy + 80*1024 + 128);
  unsigned int *tbits = (unsigned int*)(base + 176*MBy + 80*1024 + 192);
  float *partials = F(176*MBy + 512*1024);            // [32][N]
  __bf16 *ypmH = Bp(177*MBy);                         // [2][N][C]
  __bf16 *zpolH = Bp(185*MBy), *zpolL = Bp(187*MBy);  // [4][C][C] pairs
  float *Zf = F(189*MBy), *S1 = F(193*MBy), *TT = F(197*MBy), *Zf2 = F(201*MBy);

  float* outm = (float*)d_out;               // [2][C][N]
  float* attx = outm + B2 * CN;              // [2][N]
  float* atty = attx + (long)B2 * N;

  // 1) stats + prep (pixel-major adain-high, centered pairs; channel-major centered pairs; raw y high)
  k_stats<<<dim3(4 * C), dim3(256), 0, stream>>>(x, y, meanv, invs);
  k_prep<<<dim3(64, 8, 2), dim3(256), 0, stream>>>(x, meanv, invs, 0, xaH, fcH, fcL, ccH, ccL, nullptr);
  k_prep<<<dim3(64, 8, 2), dim3(256), 0, stream>>>(y, meanv, invs, 2, yaH, fcH, fcL, ccH, ccL, ypmH);

  // 2) weight conversions
  {
    const int nb = (int)(CC / 256);
    k_wcvt_h<<<nb, 256, 0, stream>>>(f_w, fwH, (int)CC);
    k_wcvt_h<<<nb, 256, 0, stream>>>(g_w, gwH, (int)CC);
    k_wcvt_h<<<nb, 256, 0, stream>>>(h_w, hwH, (int)CC);
    k_wcvt_h<<<nb, 256, 0, stream>>>(ow, owH, (int)CC);
    k_wcvt<<<nb, 256, 0, stream>>>(saf_w, sfH, sfL, (int)CC);
    k_wcvt<<<nb, 256, 0, stream>>>(sag_w, sgH, sgL, (int)CC);
  }

  // 3) cov = cc.cc^T/(n-1) via split-bf16 MFMA; finish adds 2eps*I + Gershgorin bound
  k_mm64<0,0,0><<<dim3(8, 8, 4), dim3(256), 0, stream>>>(
      ccH, ccL, ccH, ccL, covb, nullptr, nullptr, C, N, CN, CN, CC, 1.f / (float)(N - 1));
  hipMemsetAsync(tbits, 0, 4 * sizeof(unsigned int), stream);
  k_cov_finish<<<dim3(C, 4), dim3(128), 0, stream>>>(covb, tbits);
  k_scalars<<<dim3(1), dim3(8), 0, stream>>>(tbits, invt, invsqt);

  // 4) main convs (1-pass bf16; frees cc region consumers-first)
  k_mm<1,0,2><<<dim3(32, 4, 2), dim3(256), 0, stream>>>(xaH, nullptr, fwH, nullptr, nullptr, fpmH, nullptr,
      C, C, NC, 0, NC, 1.f, nullptr, nullptr, f_b, nullptr, 0);
  k_mm<1,0,2><<<dim3(32, 4, 2), dim3(256), 0, stream>>>(yaH, nullptr, gwH, nullptr, nullptr, gpmH, nullptr,
      C, C, NC, 0, NC, 1.f, nullptr, nullptr, g_b, nullptr, 0);
  k_mm<1,0,2><<<dim3(4, 32, 2), dim3(256), 0, stream>>>(hwH, nullptr, ypmH, nullptr, nullptr, hH, nullptr,
      N, C, 0, NC, CN, 1.f, nullptr, h_b, nullptr, nullptr, 0);

  // 5) Newton-Schulz (split-bf16, packed [Y|T|Z], merged Yn/Zn dispatch)
  k_ns_init<<<dim3(C, 4), dim3(256), 0, stream>>>(covb, invt, nsAh, nsAl);
  __bf16 *cah = nsAh, *cal = nsAl, *cbh = nsBh, *cbl = nsBl;
  for (int it = 0; it < NS_ITERS; ++it){
    k_mm64<1,1,0><<<dim3(8, 8, 4), dim3(256), 0, stream>>>(
        cah + 8*CC, cal + 8*CC, cah, cal, nullptr, cah + 4*CC, cal + 4*CC, C, C, CC, CC, CC, 1.f);
    k_mm64<0,1,1><<<dim3(8, 8, 8), dim3(256), 0, stream>>>(
        cah, cal, cah, cal, nullptr, cbh, cbl, C, C, CC, CC, CC, 1.f);
    __bf16* t;
    t = cah; cah = cbh; cbh = t;
    t = cal; cal = cbl; cbl = t;
  }
  // 5b) fp32 Newton polish: Z' = Z(3I - (cov/t) Z^2)/2
  k_pair2f<<<dim3((int)(4*CC/256)), 256, 0, stream>>>(cah + 8*CC, cal + 8*CC, Zf, (int)(4*CC));
  k_gemm<0,0,0><<<dim3(8, 8, 4), dim3(256), 0, stream>>>(Zf, Zf, S1, C, C, C, CC, CC, CC, 1.f, nullptr, nullptr, nullptr, 0);
  k_gemm<0,0,1><<<dim3(8, 8, 4), dim3(256), 0, stream>>>(covb, S1, TT, C, C, C, CC, CC, CC, 1.f, invt, nullptr, nullptr, 0);
  k_gemm<0,0,0><<<dim3(8, 8, 4), dim3(256), 0, stream>>>(Zf, TT, Zf2, C, C, C, CC, CC, CC, 1.f, nullptr, nullptr, nullptr, 0);
  k_wcvt<<<dim3((int)(4*CC/256)), 256, 0, stream>>>(Zf2, zpolH, zpolL, (int)(4*CC));

  // 6) zca apply: xz = invsqt * fc . Z   (3-pass, pairs out)
  k_mm<3,0,1><<<dim3(32, 4, 4), dim3(256), 0, stream>>>(fcH, fcL, zpolH, zpolL, nullptr, xzH, xzL,
      C, C, NC, CC, NC, 1.f, invsqt, nullptr, nullptr, nullptr, 0);

  // 7) self-attention blocks -> atten (3-pass throughout; energy overwrites [0,64MB))
  for (int t2 = 0; t2 < 2; ++t2){
    for (int b = 0; b < B2; ++b){
      const int z = t2 * 2 + b;
      k_mm<3,0,1><<<dim3(32, 4, 1), dim3(256), 0, stream>>>(xzH + (long)z*NC, xzL + (long)z*NC, sfH, sfL,
          nullptr, fsaH, fsaL, C, C, 0, 0, 0, 1.f, nullptr, nullptr, saf_b, nullptr, 0);
      k_mm<3,0,1><<<dim3(32, 4, 1), dim3(256), 0, stream>>>(xzH + (long)z*NC, xzL + (long)z*NC, sgH, sgL,
          nullptr, gsaH, gsaL, C, C, 0, 0, 0, 1.f, nullptr, nullptr, sag_b, nullptr, 0);
      k_mm<3,0,0><<<dim3(32, 32, 1), dim3(256), 0, stream>>>(fsaH, fsaL, gsaH, gsaL, energy, nullptr, nullptr,
          N, C, 0, 0, 0, 1.f, nullptr, nullptr, nullptr, nullptr, 0);
      k_rowstats<0><<<dim3(N), dim3(256), 0, stream>>>(energy, nullptr, nullptr, rm, rsc);
      k_colaccum<<<dim3(4, 32), dim3(256), 0, stream>>>(energy, rm, rsc, partials);
      k_colreduce<<<dim3(16), dim3(256), 0, stream>>>(partials, (t2 == 0 ? attx : atty) + (long)b * N);
    }
  }

  // 8) masks
  k_radix<<<dim3(2), dim3(256), 0, stream>>>(attx, thr);
  k_radix<<<dim3(2), dim3(256), 0, stream>>>(atty, thr + 2);
  k_mask<<<dim3(16), dim3(256), 0, stream>>>(attx, atty, thr, mxv, myv);

  // 9) main path per batch (1-pass bf16)
  for (int b = 0; b < B2; ++b){
    k_mm<1,0,0><<<dim3(32, 32, 1), dim3(256), 0, stream>>>(fpmH + (long)b*NC, nullptr, gpmH + (long)b*NC, nullptr,
        energy, nullptr, nullptr, N, C, 0, 0, 0, 1.f, nullptr, nullptr, nullptr, nullptr, 0);
    k_rowstats<1><<<dim3(N), dim3(256), 0, stream>>>(energy, mxv, myv, rm, rsc);
    k_wmask<<<dim3(N, 4), dim3(256), 0, stream>>>(energy, mxv, myv, rm, rsc, corrH);
    k_mm<1,0,2><<<dim3(32, 4, 1), dim3(256), 0, stream>>>(corrH, nullptr, hH + (long)b*CN, nullptr,
        nullptr, resH, nullptr, C, N, 0, 0, 0, 1.f, nullptr, nullptr, nullptr, nullptr, 0);
    k_mm<1,0,0><<<dim3(4, 32, 1), dim3(256), 0, stream>>>(owH, nullptr, resH, nullptr,
        outm + (long)b*CN, nullptr, nullptr, N, C, 0, 0, 0, 1.f, nullptr, ob, nullptr, x + (long)b*CN, 0);
  }
}